// Round 17
// baseline (334.351 us; speedup 1.0000x reference)
//
#include <hip/hip_runtime.h>
#include <math.h>

#define DIM 256
#define NROWS_TILE 128              // 4 waves x 32 rows
#define SPLITS 8
#define CODES_PER_SPLIT 1024        // K / SPLITS
#define CCH 32                      // codes per phase
#define NPH (CODES_PER_SPLIT / CCH) // 32 phases
#define DELTA 2.2e-3f               // > 2x rigorous |exact - hi.hi| bound (9.8e-4)

typedef __attribute__((ext_vector_type(8))) _Float16 f16x8;
typedef __attribute__((ext_vector_type(4))) _Float16 f16x4;
typedef __attribute__((ext_vector_type(4))) float f32x4;

__device__ __forceinline__ float waveReduceSum(float v) {
#pragma unroll
    for (int off = 32; off >= 1; off >>= 1) v += __shfl_xor(v, off, 64);
    return v;
}

// ---------- prep (fused): l2norm+f16 encode for BOTH x and embed, plus
// zero embed_sum|bins (contiguous region) -- replaces 2 preps + 2 memsets ----
__global__ __launch_bounds__(256) void k_prep_all(
    const float* __restrict__ x, const float* __restrict__ embed,
    _Float16* __restrict__ fnh, _Float16* __restrict__ enh,
    float* __restrict__ xnorm, float* __restrict__ enorm,
    float* __restrict__ zero_region, int nzero4, int N, int K)
{
    const int w = threadIdx.x >> 6, lane = threadIdx.x & 63;
    const int r = blockIdx.x * 4 + w;

    // zeroing: one conditional float4 store per thread
    const int gid = blockIdx.x * 256 + threadIdx.x;
    if (gid < nzero4)
        *(f32x4*)&zero_region[(size_t)gid * 4] = (f32x4){0.f, 0.f, 0.f, 0.f};

    if (r >= N + K) return;
    const bool isX = (r < N);
    const float* src = isX ? &x[(size_t)r * DIM] : &embed[(size_t)(r - N) * DIM];
    f32x4 v = *(const f32x4*)&src[lane * 4];
    float ss = waveReduceSum(v[0]*v[0] + v[1]*v[1] + v[2]*v[2] + v[3]*v[3]);
    const float n = fmaxf(sqrtf(ss), 1e-12f);
    if (lane == 0) { if (isX) xnorm[r] = n; else enorm[r - N] = n; }
    f16x4 h;
#pragma unroll
    for (int c = 0; c < 4; ++c) h[c] = (_Float16)(v[c] / n);
    _Float16* dst = isX ? &fnh[(size_t)r * DIM] : &enh[(size_t)(r - N) * DIM];
    *(f16x4*)&dst[lane * 4] = h;
}

// ---------- main: hi-only f16 MFMA GEMM-BT, B direct global->registers ----------
// grid: (N/128, SPLITS) = 1024 blocks. 4 waves x 32 rows; A in regs (64 VGPR).
// NO LDS, NO barriers: B fragments are loaded straight from global (enh is
// 4 MB: L2/L3-resident; per-phase 16 KB is L1-shared by the block's 4 waves).
// Addressing fully immediate-folded: lane reads enh[(c16+(lane&15))*256 +
// kc*32 + koff]; lanes {l,l+16,l+32,l+48} cover one row's 64B -> coalesced.
// Pipeline: QA/QB 8-load half-phase register queues -- batch h+1 issues
// before batch h is consumed (16 MFMA in shadow covers L2 latency).
// Certified-refine (as R15/R16): top-2/slot, top-4/(row,split), exact fp32
// re-dot in k_merge for rows with approx gap < DELTA.
__global__ __launch_bounds__(256, 2) void k_gemm(
    const _Float16* __restrict__ fnh, const _Float16* __restrict__ enh,
    float* __restrict__ cand_val, int* __restrict__ cand_idx)
{
    const int t = threadIdx.x;
    const int w = t >> 6, lane = t & 63;
    const int rbase = blockIdx.x * NROWS_TILE;
    const int cbase = blockIdx.y * CODES_PER_SPLIT;
    const int koff = (lane >> 4) * 8;

    // ---- A panel (hi only): wave w rows rbase+w*32 .. +31, full K ----
    f16x8 Ah[2][8];
    {
        const size_t arow = (size_t)(rbase + w * 32 + (lane & 15)) * DIM;
#pragma unroll
        for (int i = 0; i < 2; ++i)
#pragma unroll
            for (int kc = 0; kc < 8; ++kc)
                Ah[i][kc] = *(const f16x8*)&fnh[arow + (size_t)i * 16 * DIM + kc * 32 + koff];
    }

    // B prefetch pointer: half-phase h (16 codes) at gp + h*4096 f16 (8 KB)
    const _Float16* gp = enh + (size_t)(cbase + (lane & 15)) * DIM + koff;

    // per-lane-slot top-2 tracking (slot = (i,rg); code = stored + (lane&15))
    float v1[2][4], v2[2][4];
    int   c1[2][4], c2[2][4];
#pragma unroll
    for (int i = 0; i < 2; ++i)
#pragma unroll
        for (int rg = 0; rg < 4; ++rg) {
            v1[i][rg] = -2.0f; v2[i][rg] = -2.5f;
            c1[i][rg] = 0;     c2[i][rg] = 0;
        }

    const f32x4 ZERO4 = (f32x4){0.f, 0.f, 0.f, 0.f};

    // prologue: half-phase 0 into QA
    f16x8 QA[8], QB[8];
#pragma unroll
    for (int q = 0; q < 8; ++q) QA[q] = *(const f16x8*)(gp + q * 32);
    gp += 4096;

#pragma unroll 1
    for (int c = 0; c < NPH; ++c) {
        f32x4 acc[2][2];   // [ch][i]

        // prefetch half 2c+1 (ch=1) into QB; consume QA (ch=0)
#pragma unroll
        for (int q = 0; q < 8; ++q) QB[q] = *(const f16x8*)(gp + q * 32);
        gp += 4096;
#pragma unroll
        for (int kc = 0; kc < 8; ++kc) {
            if (kc == 0) {
#pragma unroll
                for (int i = 0; i < 2; ++i)
                    acc[0][i] = __builtin_amdgcn_mfma_f32_16x16x32_f16(Ah[i][0], QA[0], ZERO4, 0, 0, 0);
            } else {
#pragma unroll
                for (int i = 0; i < 2; ++i)
                    acc[0][i] = __builtin_amdgcn_mfma_f32_16x16x32_f16(Ah[i][kc], QA[kc], acc[0][i], 0, 0, 0);
            }
        }

        // prefetch next phase half 0 into QA; consume QB (ch=1)
        if (c + 1 < NPH) {
#pragma unroll
            for (int q = 0; q < 8; ++q) QA[q] = *(const f16x8*)(gp + q * 32);
        }
        gp += 4096;
#pragma unroll
        for (int kc = 0; kc < 8; ++kc) {
            if (kc == 0) {
#pragma unroll
                for (int i = 0; i < 2; ++i)
                    acc[1][i] = __builtin_amdgcn_mfma_f32_16x16x32_f16(Ah[i][0], QB[0], ZERO4, 0, 0, 0);
            } else {
#pragma unroll
                for (int i = 0; i < 2; ++i)
                    acc[1][i] = __builtin_amdgcn_mfma_f32_16x16x32_f16(Ah[i][kc], QB[kc], acc[1][i], 0, 0, 0);
            }
        }

        // top-2 update per slot; codes ascend per lane -> strict > keeps first
        const int cb = cbase + c * CCH;
#pragma unroll
        for (int ch = 0; ch < 2; ++ch)
#pragma unroll
            for (int i = 0; i < 2; ++i)
#pragma unroll
                for (int rg = 0; rg < 4; ++rg) {
                    const float vv = acc[ch][i][rg];
                    const int cd = cb + ch * 16;
                    const bool gt1 = vv > v1[i][rg];
                    const bool gt2 = vv > v2[i][rg];
                    const float nv2 = gt1 ? v1[i][rg] : (gt2 ? vv : v2[i][rg]);
                    const int   nc2 = gt1 ? c1[i][rg] : (gt2 ? cd : c2[i][rg]);
                    v2[i][rg] = nv2; c2[i][rg] = nc2;
                    v1[i][rg] = gt1 ? vv : v1[i][rg];
                    c1[i][rg] = gt1 ? cd : c1[i][rg];
                }
    }

    // epilogue: per slot, extract top-4 of the 16-lane code group
#pragma unroll
    for (int i = 0; i < 2; ++i)
#pragma unroll
        for (int rg = 0; rg < 4; ++rg) {
            float lv1 = v1[i][rg], lv2 = v2[i][rg];
            int   li1 = c1[i][rg] + (lane & 15);
            int   li2 = c2[i][rg] + (lane & 15);
            const int r = rbase + w * 32 + i * 16 + (lane >> 4) * 4 + rg;
            const size_t base = ((size_t)r * SPLITS + blockIdx.y) * 4;
#pragma unroll
            for (int p = 0; p < 4; ++p) {
                float mv = lv1; int mi = li1;
#pragma unroll
                for (int off = 1; off < 16; off <<= 1) {
                    const float ov = __shfl_xor(mv, off, 16);
                    const int oi = __shfl_xor(mi, off, 16);
                    if (ov > mv || (ov == mv && oi < mi)) { mv = ov; mi = oi; }
                }
                if ((lane & 15) == 0) {
                    cand_val[base + p] = mv;
                    cand_idx[base + p] = mi;
                }
                if (li1 == mi) {   // demote owner (indices unique)
                    lv1 = lv2; li1 = li2;
                    lv2 = -3e30f; li2 = 0x7fffffff;
                }
            }
        }
}

// ---------- merge: top-4 global, certified refine, gather + scatter ----------
__global__ __launch_bounds__(256) void k_merge(
    const float* __restrict__ x, const float* __restrict__ embed,
    const float* __restrict__ cand_val, const int* __restrict__ cand_idx,
    const float* __restrict__ xnorm, const float* __restrict__ enorm,
    float* __restrict__ quantize, float* __restrict__ ind_out,
    float* __restrict__ embed_sum, float* __restrict__ bins)
{
    const int w = threadIdx.x >> 6, lane = threadIdx.x & 63;
    const int r = blockIdx.x * 4 + w;
    const int NC = SPLITS * 4;   // 32 candidates

    float lv = -3e30f; int li = 0x7fffffff;
    if (lane < NC) {
        lv = cand_val[(size_t)r * NC + lane];
        li = cand_idx[(size_t)r * NC + lane];
    }
    float tv[4]; int ti[4];
#pragma unroll
    for (int p = 0; p < 4; ++p) {
        float mv = lv; int mi = li;
#pragma unroll
        for (int off = 1; off < 32; off <<= 1) {
            const float ov = __shfl_xor(mv, off, 32);
            const int oi = __shfl_xor(mi, off, 32);
            if (ov > mv || (ov == mv && oi < mi)) { mv = ov; mi = oi; }
        }
        mv = __shfl(mv, 0, 64);   // lanes 32-63 held -inf junk: broadcast lane 0
        mi = __shfl(mi, 0, 64);
        tv[p] = mv; ti[p] = mi;
        if (li == mi) { lv = -3e30f; li = 0x7fffffff; }   // demote owner
    }

    const float xn = xnorm[r];
    const f32x4 xv4 = *(const f32x4*)&x[(size_t)r * DIM + lane * 4];

    int ind;
    if (tv[1] < tv[0] - DELTA) {
        ind = ti[0];                       // gap certified: approx argmax is exact
    } else {
        float bv = -3e30f; int bi = 0x7fffffff;
#pragma unroll
        for (int p = 0; p < 4; ++p) {
            if (tv[p] >= tv[0] - DELTA) {  // wave-uniform
                const int idx = ti[p];
                const f32x4 ev = *(const f32x4*)&embed[(size_t)idx * DIM + lane * 4];
                const float d = xv4[0]*ev[0] + xv4[1]*ev[1] + xv4[2]*ev[2] + xv4[3]*ev[3];
                const float s = waveReduceSum(d);
                const float exact = s / (xn * enorm[idx]);
                if (exact > bv || (exact == bv && idx < bi)) { bv = exact; bi = idx; }
            }
        }
        ind = bi;
    }

    if (lane == 0) {
        ind_out[r] = (float)ind;
        atomicAdd(&bins[ind], 1.0f);
    }
    const f32x4 e = *(const f32x4*)&embed[(size_t)ind * DIM + lane * 4];
    *(f32x4*)&quantize[(size_t)r * DIM + lane * 4] = e;
    atomicAdd(&embed_sum[(size_t)ind * DIM + lane * 4 + 0], xv4[0] / xn);
    atomicAdd(&embed_sum[(size_t)ind * DIM + lane * 4 + 1], xv4[1] / xn);
    atomicAdd(&embed_sum[(size_t)ind * DIM + lane * 4 + 2], xv4[2] / xn);
    atomicAdd(&embed_sum[(size_t)ind * DIM + lane * 4 + 3], xv4[3] / xn);
}

// ---------- EMA update (en recomputed inline) ----------
__global__ __launch_bounds__(256) void k_update(const float* __restrict__ embed,
    const float* __restrict__ embed_sum, const float* __restrict__ bins,
    float* __restrict__ embed_new, int K)
{
    const int w = threadIdx.x >> 6, lane = threadIdx.x & 63;
    const int k = blockIdx.x * 4 + w;
    if (k >= K) return;
    f32x4 e = *(const f32x4*)&embed[(size_t)k * DIM + lane * 4];
    float sse = waveReduceSum(e[0]*e[0] + e[1]*e[1] + e[2]*e[2] + e[3]*e[3]);
    const float ne = fmaxf(sqrtf(sse), 1e-12f);

    const float b = bins[k];
    const float bs = (b == 0.f) ? 1.f : b;
    f32x4 s = *(const f32x4*)&embed_sum[(size_t)k * DIM + lane * 4];
    f32x4 vv;
    vv[0] = s[0] / bs; vv[1] = s[1] / bs; vv[2] = s[2] / bs; vv[3] = s[3] / bs;
    float ssv = waveReduceSum(vv[0]*vv[0] + vv[1]*vv[1] + vv[2]*vv[2] + vv[3]*vv[3]);
    const float nv = fmaxf(sqrtf(ssv), 1e-12f);

    f32x4 o;
#pragma unroll
    for (int c = 0; c < 4; ++c) {
        const float norm_c = (b == 0.f) ? (e[c] / ne) : (vv[c] / nv);
        o[c] = 0.8f * e[c] + 0.2f * norm_c;
    }
    *(f32x4*)&embed_new[(size_t)k * DIM + lane * 4] = o;
}

extern "C" void kernel_launch(void* const* d_in, const int* in_sizes, int n_in,
                              void* d_out, int out_size, void* d_ws, size_t ws_size,
                              hipStream_t stream) {
    const float* x = (const float*)d_in[0];
    const float* embed = (const float*)d_in[1];
    const int N = in_sizes[0] / DIM;   // 16384
    const int K = in_sizes[1] / DIM;   // 8192

    float* quantize  = (float*)d_out;
    float* ind_out   = quantize + (size_t)N * DIM;
    float* embed_new = ind_out + N;

    char* ws = (char*)d_ws;
    _Float16* fnh = (_Float16*)ws;                               // 8 MB
    _Float16* enh = (_Float16*)(ws + (size_t)N * DIM * 2);       // 4 MB
    char* p = ws + (size_t)N * DIM * 2 + (size_t)K * DIM * 2;
    float* xnorm    = (float*)p;                 p += (size_t)N * 4;
    float* enorm    = (float*)p;                 p += (size_t)K * 4;
    float* cand_val = (float*)p;                 p += (size_t)N * SPLITS * 4 * 4;
    int*   cand_idx = (int*)p;                   p += (size_t)N * SPLITS * 4 * 4;
    float* embed_sum = (float*)p;                // K*DIM floats (8 MB)
    float* bins      = embed_sum + (size_t)K * DIM;   // K floats, contiguous
    const int nzero4 = (K * DIM + K) / 4;        // zero embed_sum|bins as float4s

    k_prep_all<<<(N + K + 3) / 4, 256, 0, stream>>>(x, embed, fnh, enh, xnorm,
                                                    enorm, embed_sum, nzero4, N, K);

    dim3 grid(N / NROWS_TILE, SPLITS);
    k_gemm<<<grid, 256, 0, stream>>>(fnh, enh, cand_val, cand_idx);

    k_merge<<<(N + 3) / 4, 256, 0, stream>>>(x, embed, cand_val, cand_idx, xnorm,
                                             enorm, quantize, ind_out, embed_sum, bins);
    k_update<<<(K + 3) / 4, 256, 0, stream>>>(embed, embed_sum, bins, embed_new, K);
}

// Round 18
// 188.511 us; speedup vs baseline: 1.7736x; 1.7736x over previous
//
#include <hip/hip_runtime.h>
#include <math.h>

#define DIM 256
#define NROWS_TILE 128              // 4 waves x 32 rows
#define SPLITS 16
#define CODES_PER_SPLIT 512         // K / SPLITS
#define CCH 32                      // codes per phase (full K=256 staged)
#define NPH (CODES_PER_SPLIT / CCH) // 16 phases
#define BUF_F16 8192                // 16 KB: 16 frags x 512 f16 (Bh only)
#define DELTA 2.2e-3f               // > 2x rigorous |exact - hi.hi| bound (9.8e-4)

typedef __attribute__((ext_vector_type(8))) _Float16 f16x8;
typedef __attribute__((ext_vector_type(4))) _Float16 f16x4;
typedef __attribute__((ext_vector_type(4))) float f32x4;

__device__ __forceinline__ void gload16(const void* g, void* l) {
    __builtin_amdgcn_global_load_lds(
        (const __attribute__((address_space(1))) void*)g,
        (__attribute__((address_space(3))) void*)l, 16, 0, 0);
}

__device__ __forceinline__ float waveReduceSum(float v) {
#pragma unroll
    for (int off = 32; off >= 1; off >>= 1) v += __shfl_xor(v, off, 64);
    return v;
}

// ---------- prep (fused): l2norm+f16 encode for BOTH x and embed, plus
// zero embed_sum|bins (contiguous region) -- replaces 2 preps + 2 memsets ----
__global__ __launch_bounds__(256) void k_prep_all(
    const float* __restrict__ x, const float* __restrict__ embed,
    _Float16* __restrict__ fnh, _Float16* __restrict__ enh,
    float* __restrict__ xnorm, float* __restrict__ enorm,
    float* __restrict__ zero_region, int nzero4, int N, int K)
{
    const int w = threadIdx.x >> 6, lane = threadIdx.x & 63;
    const int r = blockIdx.x * 4 + w;

    // zeroing: one conditional float4 store per thread
    const int gid = blockIdx.x * 256 + threadIdx.x;
    if (gid < nzero4)
        *(f32x4*)&zero_region[(size_t)gid * 4] = (f32x4){0.f, 0.f, 0.f, 0.f};

    if (r >= N + K) return;
    const bool isX = (r < N);
    const float* src = isX ? &x[(size_t)r * DIM] : &embed[(size_t)(r - N) * DIM];
    f32x4 v = *(const f32x4*)&src[lane * 4];
    float ss = waveReduceSum(v[0]*v[0] + v[1]*v[1] + v[2]*v[2] + v[3]*v[3]);
    const float n = fmaxf(sqrtf(ss), 1e-12f);
    if (lane == 0) { if (isX) xnorm[r] = n; else enorm[r - N] = n; }
    f16x4 h;
#pragma unroll
    for (int c = 0; c < 4; ++c) h[c] = (_Float16)(v[c] / n);
    _Float16* dst = isX ? &fnh[(size_t)r * DIM] : &enh[(size_t)(r - N) * DIM];
    *(f16x4*)&dst[lane * 4] = h;
}

// ---------- main: hi-only f16 MFMA GEMM-BT (R15 structure, SPLITS=16) ----------
// grid: (N/128, 16) = 2048 blocks -> 8 available/CU, LDS caps residency at 5
// (32 KB/block): surplus co-resident blocks de-correlate read/MFMA phases so
// LDS port (41us), VALU (49us), MFMA pipe (29us) overlap instead of serialize.
// Wave owns 32 rows x K=256 in regs. Phase = 32 codes x 256 k (Bh) = 16 KB,
// ring-2, publish protocol: vmcnt(0) -> barrier -> stage(c+1) -> compute(c).
// Certified-refine: top-2/slot, top-4/(row,split); exact fp32 re-dot in merge.
__global__ __launch_bounds__(256, 2) void k_gemm(
    const _Float16* __restrict__ fnh, const _Float16* __restrict__ enh,
    float* __restrict__ cand_val, int* __restrict__ cand_idx)
{
    // buf: frag s (ch=s>>3, kc=s&7) at s*512; slot lane*8 =
    // enh[(cb+ch*16+(lane&15))*256 + kc*32 + (lane>>4)*8]
    __shared__ _Float16 smem[2][BUF_F16];   // 2 x 16 KB

    const int t = threadIdx.x;
    const int w = t >> 6, lane = t & 63;
    const int rbase = blockIdx.x * NROWS_TILE;
    const int cbase = blockIdx.y * CODES_PER_SPLIT;
    const int koff = (lane >> 4) * 8;

    // ---- A panel (hi only): wave w rows rbase+w*32 .. +31, full K ----
    f16x8 Ah[2][8];
    {
        const size_t arow = (size_t)(rbase + w * 32 + (lane & 15)) * DIM;
#pragma unroll
        for (int i = 0; i < 2; ++i)
#pragma unroll
            for (int kc = 0; kc < 8; ++kc)
                Ah[i][kc] = *(const f16x8*)&fnh[arow + (size_t)i * 16 * DIM + kc * 32 + koff];
    }
    asm volatile("s_waitcnt vmcnt(0)" ::: "memory");   // A done; vmcnt clean

    // staging roles: wave w stages frags w*4..w*4+3 (ch = w>>1, kc base = (w&1)*4)
    const int chbase = (w >> 1) * 16;
    const int kcb = (w & 1) * 4;
    const int dstoff = w * 2048;
    const _Float16* gptr = enh + (size_t)(cbase + chbase + (lane & 15)) * DIM + kcb * 32 + koff;

    // per-lane-slot top-2 tracking (slot = (i,rg); code = stored + (lane&15))
    float v1[2][4], v2[2][4];
    int   c1[2][4], c2[2][4];
#pragma unroll
    for (int i = 0; i < 2; ++i)
#pragma unroll
        for (int rg = 0; rg < 4; ++rg) {
            v1[i][rg] = -2.0f; v2[i][rg] = -2.5f;
            c1[i][rg] = 0;     c2[i][rg] = 0;
        }

    const f32x4 ZERO4 = (f32x4){0.f, 0.f, 0.f, 0.f};

    // prologue: chunk 0 in flight
    {
        _Float16* l0 = &smem[0][dstoff];
#pragma unroll
        for (int q = 0; q < 4; ++q)
            gload16(gptr + q * 32, l0 + q * 512);
        gptr += CCH * DIM;
    }

#pragma unroll 1
    for (int c = 0; c < NPH; ++c) {
        const int buf = c & 1;
        asm volatile("s_waitcnt vmcnt(0)" ::: "memory");   // publish own loads
        __builtin_amdgcn_s_barrier();
        if (c + 1 < NPH) {
            _Float16* l0 = &smem[buf ^ 1][dstoff];
#pragma unroll
            for (int q = 0; q < 4; ++q)
                gload16(gptr + q * 32, l0 + q * 512);
            gptr += CCH * DIM;
        }

        const _Float16* bufp = &smem[buf][0];
        f32x4 acc[2][2];   // [ch][i]

#pragma unroll
        for (int s = 0; s < 16; ++s) {
            const int ch = s >> 3;
            const int kc = s & 7;
            const f16x8 Bh = *(const f16x8*)(bufp + s * 512 + lane * 8);
            if (kc == 0) {
#pragma unroll
                for (int i = 0; i < 2; ++i)
                    acc[ch][i] = __builtin_amdgcn_mfma_f32_16x16x32_f16(Ah[i][0], Bh, ZERO4, 0, 0, 0);
            } else {
#pragma unroll
                for (int i = 0; i < 2; ++i)
                    acc[ch][i] = __builtin_amdgcn_mfma_f32_16x16x32_f16(Ah[i][kc], Bh, acc[ch][i], 0, 0, 0);
            }
        }

        // top-2 update per slot; codes ascend per lane -> strict > keeps first
        const int cb = cbase + c * CCH;
#pragma unroll
        for (int ch = 0; ch < 2; ++ch)
#pragma unroll
            for (int i = 0; i < 2; ++i)
#pragma unroll
                for (int rg = 0; rg < 4; ++rg) {
                    const float vv = acc[ch][i][rg];
                    const int cd = cb + ch * 16;
                    const bool gt1 = vv > v1[i][rg];
                    const bool gt2 = vv > v2[i][rg];
                    const float nv2 = gt1 ? v1[i][rg] : (gt2 ? vv : v2[i][rg]);
                    const int   nc2 = gt1 ? c1[i][rg] : (gt2 ? cd : c2[i][rg]);
                    v2[i][rg] = nv2; c2[i][rg] = nc2;
                    v1[i][rg] = gt1 ? vv : v1[i][rg];
                    c1[i][rg] = gt1 ? cd : c1[i][rg];
                }
    }

    // epilogue: per slot, extract top-4 of the 16-lane code group
#pragma unroll
    for (int i = 0; i < 2; ++i)
#pragma unroll
        for (int rg = 0; rg < 4; ++rg) {
            float lv1 = v1[i][rg], lv2 = v2[i][rg];
            int   li1 = c1[i][rg] + (lane & 15);
            int   li2 = c2[i][rg] + (lane & 15);
            const int r = rbase + w * 32 + i * 16 + (lane >> 4) * 4 + rg;
            const size_t base = ((size_t)r * SPLITS + blockIdx.y) * 4;
#pragma unroll
            for (int p = 0; p < 4; ++p) {
                float mv = lv1; int mi = li1;
#pragma unroll
                for (int off = 1; off < 16; off <<= 1) {
                    const float ov = __shfl_xor(mv, off, 16);
                    const int oi = __shfl_xor(mi, off, 16);
                    if (ov > mv || (ov == mv && oi < mi)) { mv = ov; mi = oi; }
                }
                if ((lane & 15) == 0) {
                    cand_val[base + p] = mv;
                    cand_idx[base + p] = mi;
                }
                if (li1 == mi) {   // demote owner (indices unique)
                    lv1 = lv2; li1 = li2;
                    lv2 = -3e30f; li2 = 0x7fffffff;
                }
            }
        }
}

// ---------- merge: top-4 of 64 cands, certified refine, gather + scatter ----------
__global__ __launch_bounds__(256) void k_merge(
    const float* __restrict__ x, const float* __restrict__ embed,
    const float* __restrict__ cand_val, const int* __restrict__ cand_idx,
    const float* __restrict__ xnorm, const float* __restrict__ enorm,
    float* __restrict__ quantize, float* __restrict__ ind_out,
    float* __restrict__ embed_sum, float* __restrict__ bins)
{
    const int w = threadIdx.x >> 6, lane = threadIdx.x & 63;
    const int r = blockIdx.x * 4 + w;
    // NC = SPLITS*4 = 64 candidates: exactly one per lane

    float lv = cand_val[(size_t)r * 64 + lane];
    int   li = cand_idx[(size_t)r * 64 + lane];
    float tv[4]; int ti[4];
#pragma unroll
    for (int p = 0; p < 4; ++p) {
        float mv = lv; int mi = li;
#pragma unroll
        for (int off = 1; off < 64; off <<= 1) {
            const float ov = __shfl_xor(mv, off, 64);
            const int oi = __shfl_xor(mi, off, 64);
            if (ov > mv || (ov == mv && oi < mi)) { mv = ov; mi = oi; }
        }
        tv[p] = mv; ti[p] = mi;
        if (li == mi) { lv = -3e30f; li = 0x7fffffff; }   // demote owner
    }

    const float xn = xnorm[r];
    const f32x4 xv4 = *(const f32x4*)&x[(size_t)r * DIM + lane * 4];

    int ind;
    if (tv[1] < tv[0] - DELTA) {
        ind = ti[0];                       // gap certified: approx argmax is exact
    } else {
        float bv = -3e30f; int bi = 0x7fffffff;
#pragma unroll
        for (int p = 0; p < 4; ++p) {
            if (tv[p] >= tv[0] - DELTA) {  // wave-uniform
                const int idx = ti[p];
                const f32x4 ev = *(const f32x4*)&embed[(size_t)idx * DIM + lane * 4];
                const float d = xv4[0]*ev[0] + xv4[1]*ev[1] + xv4[2]*ev[2] + xv4[3]*ev[3];
                const float s = waveReduceSum(d);
                const float exact = s / (xn * enorm[idx]);
                if (exact > bv || (exact == bv && idx < bi)) { bv = exact; bi = idx; }
            }
        }
        ind = bi;
    }

    if (lane == 0) {
        ind_out[r] = (float)ind;
        atomicAdd(&bins[ind], 1.0f);
    }
    const f32x4 e = *(const f32x4*)&embed[(size_t)ind * DIM + lane * 4];
    *(f32x4*)&quantize[(size_t)r * DIM + lane * 4] = e;
    atomicAdd(&embed_sum[(size_t)ind * DIM + lane * 4 + 0], xv4[0] / xn);
    atomicAdd(&embed_sum[(size_t)ind * DIM + lane * 4 + 1], xv4[1] / xn);
    atomicAdd(&embed_sum[(size_t)ind * DIM + lane * 4 + 2], xv4[2] / xn);
    atomicAdd(&embed_sum[(size_t)ind * DIM + lane * 4 + 3], xv4[3] / xn);
}

// ---------- EMA update (en recomputed inline) ----------
__global__ __launch_bounds__(256) void k_update(const float* __restrict__ embed,
    const float* __restrict__ embed_sum, const float* __restrict__ bins,
    float* __restrict__ embed_new, int K)
{
    const int w = threadIdx.x >> 6, lane = threadIdx.x & 63;
    const int k = blockIdx.x * 4 + w;
    if (k >= K) return;
    f32x4 e = *(const f32x4*)&embed[(size_t)k * DIM + lane * 4];
    float sse = waveReduceSum(e[0]*e[0] + e[1]*e[1] + e[2]*e[2] + e[3]*e[3]);
    const float ne = fmaxf(sqrtf(sse), 1e-12f);

    const float b = bins[k];
    const float bs = (b == 0.f) ? 1.f : b;
    f32x4 s = *(const f32x4*)&embed_sum[(size_t)k * DIM + lane * 4];
    f32x4 vv;
    vv[0] = s[0] / bs; vv[1] = s[1] / bs; vv[2] = s[2] / bs; vv[3] = s[3] / bs;
    float ssv = waveReduceSum(vv[0]*vv[0] + vv[1]*vv[1] + vv[2]*vv[2] + vv[3]*vv[3]);
    const float nv = fmaxf(sqrtf(ssv), 1e-12f);

    f32x4 o;
#pragma unroll
    for (int c = 0; c < 4; ++c) {
        const float norm_c = (b == 0.f) ? (e[c] / ne) : (vv[c] / nv);
        o[c] = 0.8f * e[c] + 0.2f * norm_c;
    }
    *(f32x4*)&embed_new[(size_t)k * DIM + lane * 4] = o;
}

extern "C" void kernel_launch(void* const* d_in, const int* in_sizes, int n_in,
                              void* d_out, int out_size, void* d_ws, size_t ws_size,
                              hipStream_t stream) {
    const float* x = (const float*)d_in[0];
    const float* embed = (const float*)d_in[1];
    const int N = in_sizes[0] / DIM;   // 16384
    const int K = in_sizes[1] / DIM;   // 8192

    float* quantize  = (float*)d_out;
    float* ind_out   = quantize + (size_t)N * DIM;
    float* embed_new = ind_out + N;

    char* ws = (char*)d_ws;
    _Float16* fnh = (_Float16*)ws;                               // 8 MB
    _Float16* enh = (_Float16*)(ws + (size_t)N * DIM * 2);       // 4 MB
    char* p = ws + (size_t)N * DIM * 2 + (size_t)K * DIM * 2;
    float* xnorm    = (float*)p;                 p += (size_t)N * 4;
    float* enorm    = (float*)p;                 p += (size_t)K * 4;
    float* cand_val = (float*)p;                 p += (size_t)N * SPLITS * 4 * 4;
    int*   cand_idx = (int*)p;                   p += (size_t)N * SPLITS * 4 * 4;
    float* embed_sum = (float*)p;                // K*DIM floats (8 MB)
    float* bins      = embed_sum + (size_t)K * DIM;   // K floats, contiguous
    const int nzero4 = (K * DIM + K) / 4;        // zero embed_sum|bins as float4s

    k_prep_all<<<(N + K + 3) / 4, 256, 0, stream>>>(x, embed, fnh, enh, xnorm,
                                                    enorm, embed_sum, nzero4, N, K);

    dim3 grid(N / NROWS_TILE, SPLITS);
    k_gemm<<<grid, 256, 0, stream>>>(fnh, enh, cand_val, cand_idx);

    k_merge<<<(N + 3) / 4, 256, 0, stream>>>(x, embed, cand_val, cand_idx, xnorm,
                                             enorm, quantize, ind_out, embed_sum, bins);
    k_update<<<(K + 3) / 4, 256, 0, stream>>>(embed, embed_sum, bins, embed_new, K);
}

// Round 19
// 134.075 us; speedup vs baseline: 2.4938x; 1.4060x over previous
//
#include <hip/hip_runtime.h>
#include <math.h>

#define DIM 256
#define NROWS_TILE 128              // 4 waves x 32 rows
#define SPLITS 8
#define CODES_PER_SPLIT 1024        // K / SPLITS
#define CCH 32                      // codes per phase (full K=256 staged)
#define NPH (CODES_PER_SPLIT / CCH) // 32 phases
#define BUF_F16 8192                // 16 KB: 16 frags x 512 f16 (Bh only)
#define DELTA 2.2e-3f               // > 2x rigorous |exact - hi.hi| bound (9.8e-4)
#define MAXR 32                     // rowlist capacity per code (Poisson max ~12)

typedef __attribute__((ext_vector_type(8))) _Float16 f16x8;
typedef __attribute__((ext_vector_type(4))) _Float16 f16x4;
typedef __attribute__((ext_vector_type(4))) float f32x4;

__device__ __forceinline__ void gload16(const void* g, void* l) {
    __builtin_amdgcn_global_load_lds(
        (const __attribute__((address_space(1))) void*)g,
        (__attribute__((address_space(3))) void*)l, 16, 0, 0);
}

__device__ __forceinline__ float waveReduceSum(float v) {
#pragma unroll
    for (int off = 32; off >= 1; off >>= 1) v += __shfl_xor(v, off, 64);
    return v;
}

// ---------- prep (fused): l2norm+f16 encode for BOTH x and embed, plus
// zero embed_sum|bins (contiguous region) ----
__global__ __launch_bounds__(256) void k_prep_all(
    const float* __restrict__ x, const float* __restrict__ embed,
    _Float16* __restrict__ fnh, _Float16* __restrict__ enh,
    float* __restrict__ xnorm, float* __restrict__ enorm,
    float* __restrict__ zero_region, int nzero4, int N, int K)
{
    const int w = threadIdx.x >> 6, lane = threadIdx.x & 63;
    const int r = blockIdx.x * 4 + w;

    const int gid = blockIdx.x * 256 + threadIdx.x;
    if (gid < nzero4)
        *(f32x4*)&zero_region[(size_t)gid * 4] = (f32x4){0.f, 0.f, 0.f, 0.f};

    if (r >= N + K) return;
    const bool isX = (r < N);
    const float* src = isX ? &x[(size_t)r * DIM] : &embed[(size_t)(r - N) * DIM];
    f32x4 v = *(const f32x4*)&src[lane * 4];
    float ss = waveReduceSum(v[0]*v[0] + v[1]*v[1] + v[2]*v[2] + v[3]*v[3]);
    const float n = fmaxf(sqrtf(ss), 1e-12f);
    if (lane == 0) { if (isX) xnorm[r] = n; else enorm[r - N] = n; }
    f16x4 h;
#pragma unroll
    for (int c = 0; c < 4; ++c) h[c] = (_Float16)(v[c] / n);
    _Float16* dst = isX ? &fnh[(size_t)r * DIM] : &enh[(size_t)(r - N) * DIM];
    *(f16x4*)&dst[lane * 4] = h;
}

// ---------- main: hi-only f16 MFMA GEMM-BT (R15 structure, verbatim) ----------
__global__ __launch_bounds__(256, 2) void k_gemm(
    const _Float16* __restrict__ fnh, const _Float16* __restrict__ enh,
    float* __restrict__ cand_val, int* __restrict__ cand_idx)
{
    __shared__ _Float16 smem[2][BUF_F16];   // 2 x 16 KB

    const int t = threadIdx.x;
    const int w = t >> 6, lane = t & 63;
    const int rbase = blockIdx.x * NROWS_TILE;
    const int cbase = blockIdx.y * CODES_PER_SPLIT;
    const int koff = (lane >> 4) * 8;

    f16x8 Ah[2][8];
    {
        const size_t arow = (size_t)(rbase + w * 32 + (lane & 15)) * DIM;
#pragma unroll
        for (int i = 0; i < 2; ++i)
#pragma unroll
            for (int kc = 0; kc < 8; ++kc)
                Ah[i][kc] = *(const f16x8*)&fnh[arow + (size_t)i * 16 * DIM + kc * 32 + koff];
    }
    asm volatile("s_waitcnt vmcnt(0)" ::: "memory");

    const int chbase = (w >> 1) * 16;
    const int kcb = (w & 1) * 4;
    const int dstoff = w * 2048;
    const _Float16* gptr = enh + (size_t)(cbase + chbase + (lane & 15)) * DIM + kcb * 32 + koff;

    float v1[2][4], v2[2][4];
    int   c1[2][4], c2[2][4];
#pragma unroll
    for (int i = 0; i < 2; ++i)
#pragma unroll
        for (int rg = 0; rg < 4; ++rg) {
            v1[i][rg] = -2.0f; v2[i][rg] = -2.5f;
            c1[i][rg] = 0;     c2[i][rg] = 0;
        }

    const f32x4 ZERO4 = (f32x4){0.f, 0.f, 0.f, 0.f};

    {
        _Float16* l0 = &smem[0][dstoff];
#pragma unroll
        for (int q = 0; q < 4; ++q)
            gload16(gptr + q * 32, l0 + q * 512);
        gptr += CCH * DIM;
    }

#pragma unroll 1
    for (int c = 0; c < NPH; ++c) {
        const int buf = c & 1;
        asm volatile("s_waitcnt vmcnt(0)" ::: "memory");
        __builtin_amdgcn_s_barrier();
        if (c + 1 < NPH) {
            _Float16* l0 = &smem[buf ^ 1][dstoff];
#pragma unroll
            for (int q = 0; q < 4; ++q)
                gload16(gptr + q * 32, l0 + q * 512);
            gptr += CCH * DIM;
        }

        const _Float16* bufp = &smem[buf][0];
        f32x4 acc[2][2];

#pragma unroll
        for (int s = 0; s < 16; ++s) {
            const int ch = s >> 3;
            const int kc = s & 7;
            const f16x8 Bh = *(const f16x8*)(bufp + s * 512 + lane * 8);
            if (kc == 0) {
#pragma unroll
                for (int i = 0; i < 2; ++i)
                    acc[ch][i] = __builtin_amdgcn_mfma_f32_16x16x32_f16(Ah[i][0], Bh, ZERO4, 0, 0, 0);
            } else {
#pragma unroll
                for (int i = 0; i < 2; ++i)
                    acc[ch][i] = __builtin_amdgcn_mfma_f32_16x16x32_f16(Ah[i][kc], Bh, acc[ch][i], 0, 0, 0);
            }
        }

        const int cb = cbase + c * CCH;
#pragma unroll
        for (int ch = 0; ch < 2; ++ch)
#pragma unroll
            for (int i = 0; i < 2; ++i)
#pragma unroll
                for (int rg = 0; rg < 4; ++rg) {
                    const float vv = acc[ch][i][rg];
                    const int cd = cb + ch * 16;
                    const bool gt1 = vv > v1[i][rg];
                    const bool gt2 = vv > v2[i][rg];
                    const float nv2 = gt1 ? v1[i][rg] : (gt2 ? vv : v2[i][rg]);
                    const int   nc2 = gt1 ? c1[i][rg] : (gt2 ? cd : c2[i][rg]);
                    v2[i][rg] = nv2; c2[i][rg] = nc2;
                    v1[i][rg] = gt1 ? vv : v1[i][rg];
                    c1[i][rg] = gt1 ? cd : c1[i][rg];
                }
    }

#pragma unroll
    for (int i = 0; i < 2; ++i)
#pragma unroll
        for (int rg = 0; rg < 4; ++rg) {
            float lv1 = v1[i][rg], lv2 = v2[i][rg];
            int   li1 = c1[i][rg] + (lane & 15);
            int   li2 = c2[i][rg] + (lane & 15);
            const int r = rbase + w * 32 + i * 16 + (lane >> 4) * 4 + rg;
            const size_t base = ((size_t)r * SPLITS + blockIdx.y) * 4;
#pragma unroll
            for (int p = 0; p < 4; ++p) {
                float mv = lv1; int mi = li1;
#pragma unroll
                for (int off = 1; off < 16; off <<= 1) {
                    const float ov = __shfl_xor(mv, off, 16);
                    const int oi = __shfl_xor(mi, off, 16);
                    if (ov > mv || (ov == mv && oi < mi)) { mv = ov; mi = oi; }
                }
                if ((lane & 15) == 0) {
                    cand_val[base + p] = mv;
                    cand_idx[base + p] = mi;
                }
                if (li1 == mi) {
                    lv1 = lv2; li1 = li2;
                    lv2 = -3e30f; li2 = 0x7fffffff;
                }
            }
        }
}

// ---------- merge: top-4 of 32, certified refine, gather, INVERTED-INDEX ----------
// Instead of 256 atomicAdds/row into embed_sum, lane 0 claims a slot via the
// bins counter (atomicAdd returns old count) and stores the ROW ID into
// rowlist[ind*MAXR+slot]; k_update gathers. Overflow (slot>=MAXR, ~never at
// Poisson lambda=2) falls back to the wave-wide atomic scatter -- correct
// because embed_sum is zeroed each call and update always adds it for
// overflowed codes.
__global__ __launch_bounds__(256) void k_merge(
    const float* __restrict__ x, const float* __restrict__ embed,
    const float* __restrict__ cand_val, const int* __restrict__ cand_idx,
    const float* __restrict__ xnorm, const float* __restrict__ enorm,
    float* __restrict__ quantize, float* __restrict__ ind_out,
    float* __restrict__ embed_sum, float* __restrict__ bins,
    int* __restrict__ rowlist)
{
    const int w = threadIdx.x >> 6, lane = threadIdx.x & 63;
    const int r = blockIdx.x * 4 + w;
    const int NC = SPLITS * 4;   // 32 candidates

    float lv = -3e30f; int li = 0x7fffffff;
    if (lane < NC) {
        lv = cand_val[(size_t)r * NC + lane];
        li = cand_idx[(size_t)r * NC + lane];
    }
    float tv[4]; int ti[4];
#pragma unroll
    for (int p = 0; p < 4; ++p) {
        float mv = lv; int mi = li;
#pragma unroll
        for (int off = 1; off < 32; off <<= 1) {
            const float ov = __shfl_xor(mv, off, 32);
            const int oi = __shfl_xor(mi, off, 32);
            if (ov > mv || (ov == mv && oi < mi)) { mv = ov; mi = oi; }
        }
        mv = __shfl(mv, 0, 64);
        mi = __shfl(mi, 0, 64);
        tv[p] = mv; ti[p] = mi;
        if (li == mi) { lv = -3e30f; li = 0x7fffffff; }
    }

    const float xn = xnorm[r];

    int ind;
    if (tv[1] < tv[0] - DELTA) {
        ind = ti[0];                       // gap certified: approx argmax is exact
    } else {
        const f32x4 xv4 = *(const f32x4*)&x[(size_t)r * DIM + lane * 4];
        float bv = -3e30f; int bi = 0x7fffffff;
#pragma unroll
        for (int p = 0; p < 4; ++p) {
            if (tv[p] >= tv[0] - DELTA) {  // wave-uniform
                const int idx = ti[p];
                const f32x4 ev = *(const f32x4*)&embed[(size_t)idx * DIM + lane * 4];
                const float d = xv4[0]*ev[0] + xv4[1]*ev[1] + xv4[2]*ev[2] + xv4[3]*ev[3];
                const float s = waveReduceSum(d);
                const float exact = s / (xn * enorm[idx]);
                if (exact > bv || (exact == bv && idx < bi)) { bv = exact; bi = idx; }
            }
        }
        ind = bi;
    }

    // claim slot in ind's rowlist (bins doubles as the cursor)
    int slot = 0;
    if (lane == 0) {
        ind_out[r] = (float)ind;
        slot = (int)atomicAdd(&bins[ind], 1.0f);
        if (slot < MAXR) rowlist[ind * MAXR + slot] = r;
    }
    slot = __shfl(slot, 0, 64);

    // gather quantize
    const f32x4 e = *(const f32x4*)&embed[(size_t)ind * DIM + lane * 4];
    *(f32x4*)&quantize[(size_t)r * DIM + lane * 4] = e;

    // overflow fallback: wave-wide atomic scatter (rare; embed_sum pre-zeroed)
    if (slot >= MAXR) {
        const f32x4 xv4 = *(const f32x4*)&x[(size_t)r * DIM + lane * 4];
        atomicAdd(&embed_sum[(size_t)ind * DIM + lane * 4 + 0], xv4[0] / xn);
        atomicAdd(&embed_sum[(size_t)ind * DIM + lane * 4 + 1], xv4[1] / xn);
        atomicAdd(&embed_sum[(size_t)ind * DIM + lane * 4 + 2], xv4[2] / xn);
        atomicAdd(&embed_sum[(size_t)ind * DIM + lane * 4 + 3], xv4[3] / xn);
    }
}

// ---------- EMA update: GATHER via rowlist (each row read exactly once) ----------
__global__ __launch_bounds__(256) void k_update(
    const float* __restrict__ x, const float* __restrict__ xnorm,
    const int* __restrict__ rowlist, const float* __restrict__ bins,
    const float* __restrict__ embed, const float* __restrict__ embed_sum,
    float* __restrict__ embed_new, int K)
{
    const int w = threadIdx.x >> 6, lane = threadIdx.x & 63;
    const int k = blockIdx.x * 4 + w;
    if (k >= K) return;

    const float bcnt = bins[k];
    const int cnt = (int)bcnt;

    f32x4 s = (f32x4){0.f, 0.f, 0.f, 0.f};
    if (cnt > MAXR)   // overflow contributions live in embed_sum (else skip 8 MB read)
        s = *(const f32x4*)&embed_sum[(size_t)k * DIM + lane * 4];

    const int nl = (cnt < MAXR) ? cnt : MAXR;
    for (int j = 0; j < nl; ++j) {
        const int r = rowlist[k * MAXR + j];
        const f32x4 xv = *(const f32x4*)&x[(size_t)r * DIM + lane * 4];
        const float xn = xnorm[r];
#pragma unroll
        for (int c = 0; c < 4; ++c) s[c] += xv[c] / xn;
    }

    f32x4 e = *(const f32x4*)&embed[(size_t)k * DIM + lane * 4];
    float sse = waveReduceSum(e[0]*e[0] + e[1]*e[1] + e[2]*e[2] + e[3]*e[3]);
    const float ne = fmaxf(sqrtf(sse), 1e-12f);

    const float bs = (cnt == 0) ? 1.f : bcnt;
    f32x4 vv;
#pragma unroll
    for (int c = 0; c < 4; ++c) vv[c] = s[c] / bs;
    float ssv = waveReduceSum(vv[0]*vv[0] + vv[1]*vv[1] + vv[2]*vv[2] + vv[3]*vv[3]);
    const float nv = fmaxf(sqrtf(ssv), 1e-12f);

    f32x4 o;
#pragma unroll
    for (int c = 0; c < 4; ++c) {
        const float norm_c = (cnt == 0) ? (e[c] / ne) : (vv[c] / nv);
        o[c] = 0.8f * e[c] + 0.2f * norm_c;
    }
    *(f32x4*)&embed_new[(size_t)k * DIM + lane * 4] = o;
}

extern "C" void kernel_launch(void* const* d_in, const int* in_sizes, int n_in,
                              void* d_out, int out_size, void* d_ws, size_t ws_size,
                              hipStream_t stream) {
    const float* x = (const float*)d_in[0];
    const float* embed = (const float*)d_in[1];
    const int N = in_sizes[0] / DIM;   // 16384
    const int K = in_sizes[1] / DIM;   // 8192

    float* quantize  = (float*)d_out;
    float* ind_out   = quantize + (size_t)N * DIM;
    float* embed_new = ind_out + N;

    char* ws = (char*)d_ws;
    _Float16* fnh = (_Float16*)ws;                               // 8 MB
    _Float16* enh = (_Float16*)(ws + (size_t)N * DIM * 2);       // 4 MB
    char* p = ws + (size_t)N * DIM * 2 + (size_t)K * DIM * 2;
    float* xnorm    = (float*)p;                 p += (size_t)N * 4;
    float* enorm    = (float*)p;                 p += (size_t)K * 4;
    float* cand_val = (float*)p;                 p += (size_t)N * SPLITS * 4 * 4;
    int*   cand_idx = (int*)p;                   p += (size_t)N * SPLITS * 4 * 4;
    int*   rowlist  = (int*)p;                   p += (size_t)K * MAXR * 4;
    float* embed_sum = (float*)p;                // K*DIM floats (8 MB)
    float* bins      = embed_sum + (size_t)K * DIM;   // K floats, contiguous
    const int nzero4 = (K * DIM + K) / 4;        // zero embed_sum|bins as float4s

    k_prep_all<<<(N + K + 3) / 4, 256, 0, stream>>>(x, embed, fnh, enh, xnorm,
                                                    enorm, embed_sum, nzero4, N, K);

    dim3 grid(N / NROWS_TILE, SPLITS);
    k_gemm<<<grid, 256, 0, stream>>>(fnh, enh, cand_val, cand_idx);

    k_merge<<<(N + 3) / 4, 256, 0, stream>>>(x, embed, cand_val, cand_idx, xnorm,
                                             enorm, quantize, ind_out, embed_sum,
                                             bins, rowlist);
    k_update<<<(K + 3) / 4, 256, 0, stream>>>(x, xnorm, rowlist, bins, embed,
                                              embed_sum, embed_new, K);
}